// Round 2
// baseline (176.480 us; speedup 1.0000x reference)
//
#include <hip/hip_runtime.h>
#include <stdint.h>

#define NR 8192
#define DIM 512
#define BM 256
#define BN 256
#define BK 32
#define NT (DIM / BK)   // 16 K-tiles

typedef unsigned short u16;
typedef __attribute__((ext_vector_type(8))) __bf16 bf16x8;
typedef __attribute__((ext_vector_type(4))) float f32x4;

static __device__ __forceinline__ u16 f2bf(float f) {
    union { float f; uint32_t u; } v; v.f = f;
    uint32_t u = v.u;
    u += 0x7FFFu + ((u >> 16) & 1u);   // RNE
    return (u16)(u >> 16);
}

static __device__ __forceinline__ void gload_lds16(const void* g, void* l) {
    __builtin_amdgcn_global_load_lds(
        (__attribute__((address_space(1))) void*)(void*)g,
        (__attribute__((address_space(3))) void*)l,
        16, 0, 0);
}

// One block per row: reciprocal norms, exact fp32 diag term, fp32->bf16
// conversion, and zero rowsum for this call.
__global__ void prep_kernel(const float* __restrict__ xi, const float* __restrict__ xj,
                            u16* __restrict__ xib, u16* __restrict__ xjb,
                            float* __restrict__ inv_ni, float* __restrict__ inv_nj,
                            float* __restrict__ diag, float* __restrict__ rowsum) {
    const int row = blockIdx.x;
    const int t = threadIdx.x;                 // 128 threads, 4 elems each
    const float4 a = ((const float4*)(xi + (size_t)row * DIM))[t];
    const float4 b = ((const float4*)(xj + (size_t)row * DIM))[t];

    float ssi = a.x*a.x + a.y*a.y + a.z*a.z + a.w*a.w;
    float ssj = b.x*b.x + b.y*b.y + b.z*b.z + b.w*b.w;
    float dot = a.x*b.x + a.y*b.y + a.z*b.z + a.w*b.w;

    ushort4 av = { f2bf(a.x), f2bf(a.y), f2bf(a.z), f2bf(a.w) };
    ushort4 bv = { f2bf(b.x), f2bf(b.y), f2bf(b.z), f2bf(b.w) };
    ((ushort4*)(xib + (size_t)row * DIM))[t] = av;
    ((ushort4*)(xjb + (size_t)row * DIM))[t] = bv;

    #pragma unroll
    for (int m = 32; m >= 1; m >>= 1) {
        ssi += __shfl_xor(ssi, m, 64);
        ssj += __shfl_xor(ssj, m, 64);
        dot += __shfl_xor(dot, m, 64);
    }
    __shared__ float red[6];
    const int wave = t >> 6, lane = t & 63;
    if (lane == 0) { red[wave*3+0] = ssi; red[wave*3+1] = ssj; red[wave*3+2] = dot; }
    __syncthreads();
    if (t == 0) {
        float si = red[0] + red[3];
        float sj = red[1] + red[4];
        float d  = red[2] + red[5];
        float ini = rsqrtf(fmaxf(si, 1e-30f));
        float inj = rsqrtf(fmaxf(sj, 1e-30f));
        inv_ni[row] = ini;
        inv_nj[row] = inj;
        diag[row] = d * ini * inj;
        rowsum[row] = 0.0f;
    }
}

// Fused NT-GEMM + exp + row-sum.
// 256x256 tile, BK=32, 8 waves (2Mx4N), 3-slot LDS ring, counted vmcnt,
// XOR-swizzled LDS (pre-swizzled global source, swizzled ds_read).
__global__ __launch_bounds__(512, 2)
void gemm_rowsum(const u16* __restrict__ A, const u16* __restrict__ B,
                 const float* __restrict__ inv_ni, const float* __restrict__ inv_nj,
                 float* __restrict__ rowsum) {
    __shared__ u16 lds[3][2][BM * BK];   // 3 ring slots x {A,B} x 16KB = 96 KB

    const int tid = threadIdx.x;
    // XCD-aware bijective swizzle: nwg=1024, 8 XCDs, 128 blocks/chunk
    const int orig = blockIdx.x;
    const int swz = (orig & 7) * 128 + (orig >> 3);
    const int by = swz >> 5, bx = swz & 31;
    const int row0 = by * BM, col0 = bx * BN;

    // ---- staging addressing (linear LDS dest; inverse-swizzled global src) ----
    // LDS linear: thread tid writes bytes [tid*16, tid*16+16) of each 8KB part.
    //   row = part*128 + (tid>>2), phys chunk = tid&3.
    // Swizzle: phys_chunk = logical_chunk ^ ((row>>1)&3)  (16B chunks, 64B rows)
    const int r_st = tid >> 2;                       // 0..127
    const int lc   = (tid & 3) ^ ((r_st >> 1) & 3);  // logical k-chunk to fetch
    const int stoff = tid * 16;                      // byte offset in a part
    const u16* pA0 = A + (size_t)(row0 + r_st)       * DIM + lc * 8;
    const u16* pA1 = A + (size_t)(row0 + 128 + r_st) * DIM + lc * 8;
    const u16* pB0 = B + (size_t)(col0 + r_st)       * DIM + lc * 8;
    const u16* pB1 = B + (size_t)(col0 + 128 + r_st) * DIM + lc * 8;

    // ---- fragment read addressing (swizzled) ----
    const int lane = tid & 63;
    const int lr = lane & 15, lk = lane >> 4;
    const int xsw = lk ^ ((lr >> 1) & 3);            // phys chunk for this lane
    const int wid = tid >> 6;
    const int wm = wid >> 2, wn = wid & 3;           // 2M x 4N waves
    const int aoff = (wm * 128 + lr) * BK + xsw * 8; // + m*512 per 16-row frag
    const int boff = (wn * 64  + lr) * BK + xsw * 8; // + n*512

    f32x4 acc[8][4] = {};

    // ---- prologue: stage tiles 0 and 1 (8 loads/thread, in tile order) ----
    {
        char* d0a = (char*)&lds[0][0][0] + stoff;
        char* d0b = (char*)&lds[0][1][0] + stoff;
        gload_lds16(pA0 +  0, d0a);
        gload_lds16(pA1 +  0, d0a + 8192);
        gload_lds16(pB0 +  0, d0b);
        gload_lds16(pB1 +  0, d0b + 8192);
        char* d1a = (char*)&lds[1][0][0] + stoff;
        char* d1b = (char*)&lds[1][1][0] + stoff;
        gload_lds16(pA0 + 32, d1a);
        gload_lds16(pA1 + 32, d1a + 8192);
        gload_lds16(pB0 + 32, d1b);
        gload_lds16(pB1 + 32, d1b + 8192);
    }

    int slot = 0;      // ring slot of current K-tile
    int s2   = 2;      // ring slot of tile t+2 (stage target)
    int goff = 64;     // global element offset of tile t+2 (= 2*BK)

// Per-tile: vmcnt(N)+barrier, then 2 phases of {ds_read, stage-issue, MFMA}.
// No intra-tile barrier needed: stage(t+2) writes slot (t+2)%3, whose previous
// contents (tile t-1) were fully consumed before tile t's entry barrier.
#define TILE_BODY(VMSTR, DO_STAGE)                                             \
  do {                                                                         \
    asm volatile("s_waitcnt vmcnt(" VMSTR ")\ns_barrier" ::: "memory");        \
    const u16* As_ = &lds[slot][0][0];                                         \
    const u16* Bs_ = &lds[slot][1][0];                                         \
    bf16x8 af[4], bg[4];                                                       \
    _Pragma("unroll") for (int n = 0; n < 4; ++n)                              \
      bg[n] = *(const bf16x8*)(Bs_ + boff + n * 512);                          \
    _Pragma("unroll") for (int m = 0; m < 4; ++m)                              \
      af[m] = *(const bf16x8*)(As_ + aoff + m * 512);                          \
    if (DO_STAGE) {                                                            \
      char* da = (char*)&lds[s2][0][0] + stoff;                                \
      gload_lds16(pA0 + goff, da);                                             \
      gload_lds16(pA1 + goff, da + 8192);                                      \
    }                                                                          \
    __builtin_amdgcn_s_setprio(1);                                             \
    _Pragma("unroll") for (int m = 0; m < 4; ++m)                              \
      _Pragma("unroll") for (int n = 0; n < 4; ++n)                            \
        acc[m][n] = __builtin_amdgcn_mfma_f32_16x16x32_bf16(                   \
            af[m], bg[n], acc[m][n], 0, 0, 0);                                 \
    __builtin_amdgcn_s_setprio(0);                                             \
    _Pragma("unroll") for (int m = 0; m < 4; ++m)                              \
      af[m] = *(const bf16x8*)(As_ + aoff + (4 + m) * 512);                    \
    if (DO_STAGE) {                                                            \
      char* db = (char*)&lds[s2][1][0] + stoff;                                \
      gload_lds16(pB0 + goff, db);                                             \
      gload_lds16(pB1 + goff, db + 8192);                                      \
      goff += 32;                                                              \
    }                                                                          \
    __builtin_amdgcn_s_setprio(1);                                             \
    _Pragma("unroll") for (int m = 0; m < 4; ++m)                              \
      _Pragma("unroll") for (int n = 0; n < 4; ++n)                            \
        acc[4 + m][n] = __builtin_amdgcn_mfma_f32_16x16x32_bf16(               \
            af[m], bg[n], acc[4 + m][n], 0, 0, 0);                             \
    __builtin_amdgcn_s_setprio(0);                                             \
    slot = (slot == 2) ? 0 : slot + 1;                                         \
    s2   = (s2   == 2) ? 0 : s2   + 1;                                         \
  } while (0)

    #pragma unroll 1
    for (int t = 0; t < NT - 2; ++t)     // tiles 0..13: stage t+2, vmcnt(4)
        TILE_BODY("4", true);
    TILE_BODY("4", false);               // tile 14: tile 15 still in flight
    TILE_BODY("0", false);               // tile 15: drain
#undef TILE_BODY

    // ---- epilogue: cosine scale, exp, row-reduce, one atomic per row ----
    float inj[4];
    #pragma unroll
    for (int n = 0; n < 4; ++n)
        inj[n] = inv_nj[col0 + wn * 64 + n * 16 + lr];

    #pragma unroll
    for (int m = 0; m < 8; ++m) {
        #pragma unroll
        for (int e = 0; e < 4; ++e) {
            const int row = row0 + wm * 128 + m * 16 + lk * 4 + e;
            const float in_i = inv_ni[row];
            float s = 0.0f;
            #pragma unroll
            for (int n = 0; n < 4; ++n)
                s += __expf(acc[m][n][e] * in_i * inj[n]);
            s += __shfl_xor(s, 1, 64);
            s += __shfl_xor(s, 2, 64);
            s += __shfl_xor(s, 4, 64);
            s += __shfl_xor(s, 8, 64);
            if (lr == 0)
                atomicAdd(&rowsum[row], s);
        }
    }
}

__global__ void finalize(const float* __restrict__ rowsum,
                         const float* __restrict__ diag,
                         float* __restrict__ out) {
    const float E1 = 2.7182818284590452f;  // exp(1/TAU)
    float acc = 0.0f;
    for (int i = threadIdx.x; i < NR; i += 256)
        acc += __logf(rowsum[i] - E1) - diag[i];
    #pragma unroll
    for (int m = 32; m >= 1; m >>= 1)
        acc += __shfl_xor(acc, m, 64);
    __shared__ float red[4];
    const int wave = threadIdx.x >> 6, lane = threadIdx.x & 63;
    if (lane == 0) red[wave] = acc;
    __syncthreads();
    if (threadIdx.x == 0)
        out[0] = (red[0] + red[1] + red[2] + red[3]) * (1.0f / NR);
}

extern "C" void kernel_launch(void* const* d_in, const int* in_sizes, int n_in,
                              void* d_out, int out_size, void* d_ws, size_t ws_size,
                              hipStream_t stream) {
    const float* xi = (const float*)d_in[0];
    const float* xj = (const float*)d_in[1];

    char* ws = (char*)d_ws;
    u16* xib = (u16*)ws;                                // 8 MB
    u16* xjb = xib + (size_t)NR * DIM;                  // 8 MB
    float* inv_ni = (float*)(xjb + (size_t)NR * DIM);   // 32 KB
    float* inv_nj = inv_ni + NR;
    float* diag   = inv_nj + NR;
    float* rowsum = diag + NR;

    prep_kernel<<<NR, 128, 0, stream>>>(xi, xj, xib, xjb, inv_ni, inv_nj, diag, rowsum);
    gemm_rowsum<<<(NR / BM) * (NR / BN), 512, 0, stream>>>(xib, xjb, inv_ni, inv_nj, rowsum);
    finalize<<<1, 256, 0, stream>>>(rowsum, diag, (float*)d_out);
}

// Round 3
// 154.927 us; speedup vs baseline: 1.1391x; 1.1391x over previous
//
#include <hip/hip_runtime.h>
#include <stdint.h>

#define NR 8192
#define DIM 512
#define BM 256
#define BN 256
#define BK 64
#define NT (DIM / BK)   // 8 K-tiles

typedef unsigned short u16;
typedef __attribute__((ext_vector_type(8))) __bf16 bf16x8;
typedef __attribute__((ext_vector_type(4))) float f32x4;

static __device__ __forceinline__ u16 f2bf(float f) {
    union { float f; uint32_t u; } v; v.f = f;
    uint32_t u = v.u;
    u += 0x7FFFu + ((u >> 16) & 1u);   // RNE
    return (u16)(u >> 16);
}

static __device__ __forceinline__ void gload_lds16(const void* g, void* l) {
    __builtin_amdgcn_global_load_lds(
        (__attribute__((address_space(1))) void*)(void*)g,
        (__attribute__((address_space(3))) void*)l,
        16, 0, 0);
}

// One block per row: reciprocal norms, exact fp32 diag term, fp32->bf16
// conversion, and zero rowsum for this call.
__global__ void prep_kernel(const float* __restrict__ xi, const float* __restrict__ xj,
                            u16* __restrict__ xib, u16* __restrict__ xjb,
                            float* __restrict__ inv_ni, float* __restrict__ inv_nj,
                            float* __restrict__ diag, float* __restrict__ rowsum) {
    const int row = blockIdx.x;
    const int t = threadIdx.x;                 // 128 threads, 4 elems each
    const float4 a = ((const float4*)(xi + (size_t)row * DIM))[t];
    const float4 b = ((const float4*)(xj + (size_t)row * DIM))[t];

    float ssi = a.x*a.x + a.y*a.y + a.z*a.z + a.w*a.w;
    float ssj = b.x*b.x + b.y*b.y + b.z*b.z + b.w*b.w;
    float dot = a.x*b.x + a.y*b.y + a.z*b.z + a.w*b.w;

    ushort4 av = { f2bf(a.x), f2bf(a.y), f2bf(a.z), f2bf(a.w) };
    ushort4 bv = { f2bf(b.x), f2bf(b.y), f2bf(b.z), f2bf(b.w) };
    ((ushort4*)(xib + (size_t)row * DIM))[t] = av;
    ((ushort4*)(xjb + (size_t)row * DIM))[t] = bv;

    #pragma unroll
    for (int m = 32; m >= 1; m >>= 1) {
        ssi += __shfl_xor(ssi, m, 64);
        ssj += __shfl_xor(ssj, m, 64);
        dot += __shfl_xor(dot, m, 64);
    }
    __shared__ float red[6];
    const int wave = t >> 6, lane = t & 63;
    if (lane == 0) { red[wave*3+0] = ssi; red[wave*3+1] = ssj; red[wave*3+2] = dot; }
    __syncthreads();
    if (t == 0) {
        float si = red[0] + red[3];
        float sj = red[1] + red[4];
        float d  = red[2] + red[5];
        float ini = rsqrtf(fmaxf(si, 1e-30f));
        float inj = rsqrtf(fmaxf(sj, 1e-30f));
        inv_ni[row] = ini;
        inv_nj[row] = inj;
        diag[row] = d * ini * inj;
        rowsum[row] = 0.0f;
    }
}

// Fused NT-GEMM + exp + row-sum.
// 256x256 tile, BK=64, 8 waves (2Mx4N), 4-phase schedule, double-buffered
// K-half units (SA0/SA1/SB0/SB1), counted vmcnt(4), XOR-swizzled LDS.
//
// LDS units: lds[op][kk][parity][256 rows][32 k] bf16, 16 KB each, 8 units.
// Phase p=(kk,nh) of tile t: { ds_read frags; stage unit for t+1; barrier;
//   lgkmcnt(0); setprio(1); 16 MFMA; setprio(0); [vmcnt(4) @ph1,ph3]; barrier }
// Stage order SA0',SB0',SA1',SB1' at ph0..3 => every unit has 3-4 phases of
// latency cover; vmcnt(4) at end-ph1 forces SA1',SB1' landed (needed ph2),
// at end-ph3 forces SA0',SB0' landed (needed next ph0). Unit overwrite happens
// >=4 phases (and 7+ barriers) after its last read one tile earlier.
__global__ __launch_bounds__(512, 2)
void gemm_rowsum(const u16* __restrict__ A, const u16* __restrict__ B,
                 const float* __restrict__ inv_ni, const float* __restrict__ inv_nj,
                 float* __restrict__ rowsum) {
    __shared__ u16 lds[8][8192];   // [op*4 + kk*2 + parity][256*32] = 128 KB
    char* const ldsb = (char*)&lds[0][0];

    const int tid = threadIdx.x;
    // XCD-aware, L2-aware mapping: xcd = orig&7 gets 128 blocks ordered
    // by-fastest so 32 concurrent blocks = 4 row-panels x 8 col-panels
    // (A 1MB + B 2MB = 3MB < 4MB per-XCD L2).
    const int orig = blockIdx.x;
    const int xcd = orig & 7, k = orig >> 3;
    const int by = xcd * 4 + (k & 3);
    const int bx = k >> 2;
    const int row0 = by * BM, col0 = bx * BN;

    // ---- staging addressing (linear LDS dest; inverse-swizzled global src) ----
    // Unit rows are 64B (4 chunks of 16B). Swizzle: phys_chunk = c ^ (row&3).
    const int st_row = tid >> 2;                       // 0..127
    const int st_c   = (tid & 3) ^ (st_row & 3);       // logical chunk to fetch
    const u16* gA = A + (size_t)(row0 + st_row) * DIM + st_c * 8;
    const u16* gB = B + (size_t)(col0 + st_row) * DIM + st_c * 8;
    const int stoff = tid * 16;

    // ---- fragment read addressing (swizzled) ----
    const int lane = tid & 63;
    const int lr = lane & 15, lk = lane >> 4;
    const int wid = tid >> 6;
    const int wm = wid >> 2, wn = wid & 3;             // 2M x 4N waves
    const int axoff = lr * 64 + ((lk ^ (lr & 3)) * 16);  // byte off within unit row block

    f32x4 acc[8][4] = {};
    bf16x8 af[8], bg[2];

#define UNIT(OP, KK, PI) (ldsb + (((OP)*4 + (KK)*2 + (PI)) * 16384))

#define STAGE(OP, KK, PN, TN) do {                                             \
    const u16* gsrc = ((OP) ? gB : gA) + (TN) * BK + (KK) * 32;                \
    char* dst = UNIT(OP, KK, PN) + stoff;                                      \
    gload_lds16(gsrc, dst);                                                    \
    gload_lds16(gsrc + 128 * DIM, dst + 8192);                                 \
} while (0)

#define READ_AF(KK, PI) do {                                                   \
    const char* u = UNIT(0, KK, PI) + wm * 8192 + axoff;                       \
    _Pragma("unroll") for (int m = 0; m < 8; ++m)                              \
        af[m] = *(const bf16x8*)(u + m * 1024);                                \
} while (0)

#define READ_BG(KK, NH, PI) do {                                               \
    const char* u = UNIT(1, KK, PI) + wn * 4096 + (NH) * 2048 + axoff;         \
    bg[0] = *(const bf16x8*)(u);                                               \
    bg[1] = *(const bf16x8*)(u + 1024);                                        \
} while (0)

#define MFMA16(NH) do {                                                        \
    __builtin_amdgcn_s_setprio(1);                                             \
    _Pragma("unroll") for (int m = 0; m < 8; ++m) {                            \
        acc[m][(NH)*2+0] = __builtin_amdgcn_mfma_f32_16x16x32_bf16(            \
            af[m], bg[0], acc[m][(NH)*2+0], 0, 0, 0);                          \
        acc[m][(NH)*2+1] = __builtin_amdgcn_mfma_f32_16x16x32_bf16(            \
            af[m], bg[1], acc[m][(NH)*2+1], 0, 0, 0);                          \
    }                                                                          \
    __builtin_amdgcn_s_setprio(0);                                             \
} while (0)

    // ---- prologue: stage tile 0's four units, wait for SA0/SB0 ----
    STAGE(0, 0, 0, 0);
    STAGE(1, 0, 0, 0);
    STAGE(0, 1, 0, 0);
    STAGE(1, 1, 0, 0);
    asm volatile("s_waitcnt vmcnt(4)" ::: "memory");
    __builtin_amdgcn_s_barrier();

    #pragma unroll 1
    for (int t = 0; t < NT; ++t) {
        const int pi = t & 1, pn = pi ^ 1;
        const bool st = (t < NT - 1);
        // ---- ph0: kk=0, nh=0 ----
        READ_AF(0, pi);
        READ_BG(0, 0, pi);
        if (st) STAGE(0, 0, pn, t + 1);
        __builtin_amdgcn_s_barrier();
        asm volatile("s_waitcnt lgkmcnt(0)" ::: "memory");
        MFMA16(0);
        __builtin_amdgcn_s_barrier();
        // ---- ph1: kk=0, nh=1 ----
        READ_BG(0, 1, pi);
        if (st) STAGE(1, 0, pn, t + 1);
        __builtin_amdgcn_s_barrier();
        asm volatile("s_waitcnt lgkmcnt(0)" ::: "memory");
        MFMA16(1);
        if (st) asm volatile("s_waitcnt vmcnt(4)" ::: "memory");
        else    asm volatile("s_waitcnt vmcnt(0)" ::: "memory");
        __builtin_amdgcn_s_barrier();
        // ---- ph2: kk=1, nh=0 ----
        READ_AF(1, pi);
        READ_BG(1, 0, pi);
        if (st) STAGE(0, 1, pn, t + 1);
        __builtin_amdgcn_s_barrier();
        asm volatile("s_waitcnt lgkmcnt(0)" ::: "memory");
        MFMA16(0);
        __builtin_amdgcn_s_barrier();
        // ---- ph3: kk=1, nh=1 ----
        READ_BG(1, 1, pi);
        if (st) STAGE(1, 1, pn, t + 1);
        __builtin_amdgcn_s_barrier();
        asm volatile("s_waitcnt lgkmcnt(0)" ::: "memory");
        MFMA16(1);
        if (st) asm volatile("s_waitcnt vmcnt(4)" ::: "memory");
        __builtin_amdgcn_s_barrier();
    }
#undef UNIT
#undef STAGE
#undef READ_AF
#undef READ_BG
#undef MFMA16

    // ---- epilogue: cosine scale, exp, row-reduce, one atomic per row ----
    float inj[4];
    #pragma unroll
    for (int n = 0; n < 4; ++n)
        inj[n] = inv_nj[col0 + wn * 64 + n * 16 + lr];

    #pragma unroll
    for (int m = 0; m < 8; ++m) {
        #pragma unroll
        for (int e = 0; e < 4; ++e) {
            const int row = row0 + wm * 128 + m * 16 + lk * 4 + e;
            const float in_i = inv_ni[row];
            float s = 0.0f;
            #pragma unroll
            for (int n = 0; n < 4; ++n)
                s += __expf(acc[m][n][e] * in_i * inj[n]);
            s += __shfl_xor(s, 1, 64);
            s += __shfl_xor(s, 2, 64);
            s += __shfl_xor(s, 4, 64);
            s += __shfl_xor(s, 8, 64);
            if (lr == 0)
                atomicAdd(&rowsum[row], s);
        }
    }
}

__global__ void finalize(const float* __restrict__ rowsum,
                         const float* __restrict__ diag,
                         float* __restrict__ out) {
    const float E1 = 2.7182818284590452f;  // exp(1/TAU)
    float acc = 0.0f;
    for (int i = threadIdx.x; i < NR; i += 256)
        acc += __logf(rowsum[i] - E1) - diag[i];
    #pragma unroll
    for (int m = 32; m >= 1; m >>= 1)
        acc += __shfl_xor(acc, m, 64);
    __shared__ float red[4];
    const int wave = threadIdx.x >> 6, lane = threadIdx.x & 63;
    if (lane == 0) red[wave] = acc;
    __syncthreads();
    if (threadIdx.x == 0)
        out[0] = (red[0] + red[1] + red[2] + red[3]) * (1.0f / NR);
}

extern "C" void kernel_launch(void* const* d_in, const int* in_sizes, int n_in,
                              void* d_out, int out_size, void* d_ws, size_t ws_size,
                              hipStream_t stream) {
    const float* xi = (const float*)d_in[0];
    const float* xj = (const float*)d_in[1];

    char* ws = (char*)d_ws;
    u16* xib = (u16*)ws;                                // 8 MB
    u16* xjb = xib + (size_t)NR * DIM;                  // 8 MB
    float* inv_ni = (float*)(xjb + (size_t)NR * DIM);   // 32 KB
    float* inv_nj = inv_ni + NR;
    float* diag   = inv_nj + NR;
    float* rowsum = diag + NR;

    prep_kernel<<<NR, 128, 0, stream>>>(xi, xj, xib, xjb, inv_ni, inv_nj, diag, rowsum);
    gemm_rowsum<<<(NR / BM) * (NR / BN), 512, 0, stream>>>(xib, xjb, inv_ni, inv_nj, rowsum);
    finalize<<<1, 256, 0, stream>>>(rowsum, diag, (float*)d_out);
}

// Round 4
// 142.564 us; speedup vs baseline: 1.2379x; 1.0867x over previous
//
#include <hip/hip_runtime.h>
#include <stdint.h>

#define NR 8192
#define DIM 512
#define BM 256
#define BN 256
#define BK 64
#define NT (DIM / BK)   // 8 K-tiles

typedef unsigned short u16;
typedef __attribute__((ext_vector_type(8))) __bf16 bf16x8;
typedef __attribute__((ext_vector_type(4))) float f32x4;

static __device__ __forceinline__ u16 f2bf(float f) {
    union { float f; uint32_t u; } v; v.f = f;
    uint32_t u = v.u;
    u += 0x7FFFu + ((u >> 16) & 1u);   // RNE
    return (u16)(u >> 16);
}

static __device__ __forceinline__ void gload_lds16(const void* g, void* l) {
    __builtin_amdgcn_global_load_lds(
        (__attribute__((address_space(1))) void*)(void*)g,
        (__attribute__((address_space(3))) void*)l,
        16, 0, 0);
}

// One block per row: reciprocal norms, exact fp32 diag term, fp32->bf16
// conversion, and zero rowsum for this call.
__global__ void prep_kernel(const float* __restrict__ xi, const float* __restrict__ xj,
                            u16* __restrict__ xib, u16* __restrict__ xjb,
                            float* __restrict__ inv_ni, float* __restrict__ inv_nj,
                            float* __restrict__ diag, float* __restrict__ rowsum) {
    const int row = blockIdx.x;
    const int t = threadIdx.x;                 // 128 threads, 4 elems each
    const float4 a = ((const float4*)(xi + (size_t)row * DIM))[t];
    const float4 b = ((const float4*)(xj + (size_t)row * DIM))[t];

    float ssi = a.x*a.x + a.y*a.y + a.z*a.z + a.w*a.w;
    float ssj = b.x*b.x + b.y*b.y + b.z*b.z + b.w*b.w;
    float dot = a.x*b.x + a.y*b.y + a.z*b.z + a.w*b.w;

    ushort4 av = { f2bf(a.x), f2bf(a.y), f2bf(a.z), f2bf(a.w) };
    ushort4 bv = { f2bf(b.x), f2bf(b.y), f2bf(b.z), f2bf(b.w) };
    ((ushort4*)(xib + (size_t)row * DIM))[t] = av;
    ((ushort4*)(xjb + (size_t)row * DIM))[t] = bv;

    #pragma unroll
    for (int m = 32; m >= 1; m >>= 1) {
        ssi += __shfl_xor(ssi, m, 64);
        ssj += __shfl_xor(ssj, m, 64);
        dot += __shfl_xor(dot, m, 64);
    }
    __shared__ float red[6];
    const int wave = t >> 6, lane = t & 63;
    if (lane == 0) { red[wave*3+0] = ssi; red[wave*3+1] = ssj; red[wave*3+2] = dot; }
    __syncthreads();
    if (t == 0) {
        float si = red[0] + red[3];
        float sj = red[1] + red[4];
        float d  = red[2] + red[5];
        float ini = rsqrtf(fmaxf(si, 1e-30f));
        float inj = rsqrtf(fmaxf(sj, 1e-30f));
        inv_ni[row] = ini;
        inv_nj[row] = inj;
        diag[row] = d * ini * inj;
        rowsum[row] = 0.0f;
    }
}

// Fused NT-GEMM + exp + row-sum.
// 256x256 tile, BK=64, 8 waves (2Mx4N), 4 balanced phases per K-tile,
// double-buffered K-half units, counted vmcnt(4), conflict-free XOR swizzle
// (key = (row>>1)&3 on 16B chunks — round-2-verified 0 conflicts).
// Phase p: { 8 or 4 ds_read_b128; 1 stage unit (2 gload_lds); barrier;
//            lgkmcnt(0); setprio(1); 16 MFMA (m-half x 4n); setprio(0);
//            [vmcnt(4) at ph1/ph3]; barrier }
__global__ __launch_bounds__(512, 2)
void gemm_rowsum(const u16* __restrict__ A, const u16* __restrict__ B,
                 const float* __restrict__ inv_ni, const float* __restrict__ inv_nj,
                 float* __restrict__ rowsum) {
    __shared__ u16 lds[8][8192];   // 8 units x 16 KB = 128 KB
    char* const ldsA = (char*)&lds[0][0];   // units (kk*2+parity) for A: 0..64K
    char* const ldsB = (char*)&lds[4][0];   // units for B: 0..64K off ldsB

    const int tid = threadIdx.x;
    // XCD-aware, L2-aware: 32 concurrent blocks/XCD = 4 row-panels x 8
    // col-panels -> A 1MB + B 2MB = 3MB < 4MB per-XCD L2.
    const int orig = blockIdx.x;
    const int xcd = orig & 7, k = orig >> 3;
    const int by = xcd * 4 + (k & 3);
    const int bx = k >> 2;
    const int row0 = by * BM, col0 = bx * BN;

    // ---- staging (linear LDS dest; inverse-swizzled global src) ----
    // Unit rows = 64B (4 x 16B chunks). phys_chunk = logical ^ ((row>>1)&3).
    const int st_row = tid >> 2;                          // 0..127
    const int st_c   = (tid & 3) ^ ((st_row >> 1) & 3);   // global k-chunk
    const u16* gA = A + (size_t)(row0 + st_row) * DIM + st_c * 8;
    const u16* gB = B + (size_t)(col0 + st_row) * DIM + st_c * 8;
    const int stoff = tid * 16;

    // ---- fragment reads (swizzled; 2-way max -> conflict-free) ----
    const int lane = tid & 63;
    const int lr = lane & 15, lk = lane >> 4;
    const int xsw = lk ^ ((lr >> 1) & 3);
    const int wid = tid >> 6;
    const int wm = wid >> 2, wn = wid & 3;                // 2M x 4N waves
    const int aoff = wm * 8192 + lr * 64 + xsw * 16;      // + unit*16K + m*1K
    const int boff = wn * 4096 + lr * 64 + xsw * 16;      // + unit*16K + n*1K

    f32x4 acc[8][4] = {};
    bf16x8 af[4], bg[4];

#define STAGE_A(KK, PN, TN) do {                                               \
    char* dst = ldsA + ((KK)*2 + (PN)) * 16384 + stoff;                        \
    const u16* g = gA + (TN) * BK + (KK) * 32;                                 \
    gload_lds16(g, dst);                                                       \
    gload_lds16(g + 128 * DIM, dst + 8192);                                    \
} while (0)

#define STAGE_B(KK, PN, TN) do {                                               \
    char* dst = ldsB + ((KK)*2 + (PN)) * 16384 + stoff;                        \
    const u16* g = gB + (TN) * BK + (KK) * 32;                                 \
    gload_lds16(g, dst);                                                       \
    gload_lds16(g + 128 * DIM, dst + 8192);                                    \
} while (0)

#define READ_AF(KK, PI, MH) do {                                               \
    const char* u = ldsA + ((KK)*2 + (PI)) * 16384 + aoff + (MH) * 4096;       \
    _Pragma("unroll") for (int m = 0; m < 4; ++m)                              \
        af[m] = *(const bf16x8*)(u + m * 1024);                                \
} while (0)

#define READ_BG(KK, PI) do {                                                   \
    const char* u = ldsB + ((KK)*2 + (PI)) * 16384 + boff;                     \
    _Pragma("unroll") for (int n = 0; n < 4; ++n)                              \
        bg[n] = *(const bf16x8*)(u + n * 1024);                                \
} while (0)

#define MFMA16(MH) do {                                                        \
    __builtin_amdgcn_s_setprio(1);                                             \
    _Pragma("unroll") for (int m = 0; m < 4; ++m)                              \
        _Pragma("unroll") for (int n = 0; n < 4; ++n)                          \
            acc[(MH)*4 + m][n] = __builtin_amdgcn_mfma_f32_16x16x32_bf16(      \
                af[m], bg[n], acc[(MH)*4 + m][n], 0, 0, 0);                    \
    __builtin_amdgcn_s_setprio(0);                                             \
} while (0)

#define LGKM0()  asm volatile("s_waitcnt lgkmcnt(0)" ::: "memory")
#define VMCNT(N) asm volatile("s_waitcnt vmcnt(" #N ")" ::: "memory")
#define BAR()    __builtin_amdgcn_s_barrier()

    // ---- prologue: stage tile 0's four units; wait A0/B0 ----
    STAGE_A(0, 0, 0);
    STAGE_B(0, 0, 0);
    STAGE_A(1, 0, 0);
    STAGE_B(1, 0, 0);
    VMCNT(4);
    BAR();

    #pragma unroll
    for (int t = 0; t < NT; ++t) {
        const int pi = t & 1, pn = pi ^ 1;
        const bool st = (t < NT - 1);
        // ph0: kk=0, m-half 0
        READ_AF(0, pi, 0);
        READ_BG(0, pi);
        if (st) STAGE_A(0, pn, t + 1);
        BAR(); LGKM0();
        MFMA16(0);
        BAR();
        // ph1: kk=0, m-half 1
        READ_AF(0, pi, 1);
        if (st) STAGE_B(0, pn, t + 1);
        BAR(); LGKM0();
        MFMA16(1);
        if (st) VMCNT(4); else VMCNT(0);   // A1/B1 of this tile landed
        BAR();
        // ph2: kk=1, m-half 0
        READ_AF(1, pi, 0);
        READ_BG(1, pi);
        if (st) STAGE_A(1, pn, t + 1);
        BAR(); LGKM0();
        MFMA16(0);
        BAR();
        // ph3: kk=1, m-half 1
        READ_AF(1, pi, 1);
        if (st) STAGE_B(1, pn, t + 1);
        BAR(); LGKM0();
        MFMA16(1);
        if (st) VMCNT(4);                  // A0'/B0' of next tile landed
        BAR();
    }
#undef STAGE_A
#undef STAGE_B
#undef READ_AF
#undef READ_BG
#undef MFMA16
#undef LGKM0
#undef VMCNT
#undef BAR

    // ---- epilogue: cosine scale, exp, row-reduce, one atomic per row ----
    float inj[4];
    #pragma unroll
    for (int n = 0; n < 4; ++n)
        inj[n] = inv_nj[col0 + wn * 64 + n * 16 + lr];

    #pragma unroll
    for (int m = 0; m < 8; ++m) {
        #pragma unroll
        for (int e = 0; e < 4; ++e) {
            const int row = row0 + wm * 128 + m * 16 + lk * 4 + e;
            const float in_i = inv_ni[row];
            float s = 0.0f;
            #pragma unroll
            for (int n = 0; n < 4; ++n)
                s += __expf(acc[m][n][e] * in_i * inj[n]);
            s += __shfl_xor(s, 1, 64);
            s += __shfl_xor(s, 2, 64);
            s += __shfl_xor(s, 4, 64);
            s += __shfl_xor(s, 8, 64);
            if (lr == 0)
                atomicAdd(&rowsum[row], s);
        }
    }
}

__global__ void finalize(const float* __restrict__ rowsum,
                         const float* __restrict__ diag,
                         float* __restrict__ out) {
    const float E1 = 2.7182818284590452f;  // exp(1/TAU)
    float acc = 0.0f;
    for (int i = threadIdx.x; i < NR; i += 256)
        acc += __logf(rowsum[i] - E1) - diag[i];
    #pragma unroll
    for (int m = 32; m >= 1; m >>= 1)
        acc += __shfl_xor(acc, m, 64);
    __shared__ float red[4];
    const int wave = threadIdx.x >> 6, lane = threadIdx.x & 63;
    if (lane == 0) red[wave] = acc;
    __syncthreads();
    if (threadIdx.x == 0)
        out[0] = (red[0] + red[1] + red[2] + red[3]) * (1.0f / NR);
}

extern "C" void kernel_launch(void* const* d_in, const int* in_sizes, int n_in,
                              void* d_out, int out_size, void* d_ws, size_t ws_size,
                              hipStream_t stream) {
    const float* xi = (const float*)d_in[0];
    const float* xj = (const float*)d_in[1];

    char* ws = (char*)d_ws;
    u16* xib = (u16*)ws;                                // 8 MB
    u16* xjb = xib + (size_t)NR * DIM;                  // 8 MB
    float* inv_ni = (float*)(xjb + (size_t)NR * DIM);   // 32 KB
    float* inv_nj = inv_ni + NR;
    float* diag   = inv_nj + NR;
    float* rowsum = diag + NR;

    prep_kernel<<<NR, 128, 0, stream>>>(xi, xj, xib, xjb, inv_ni, inv_nj, diag, rowsum);
    gemm_rowsum<<<(NR / BM) * (NR / BN), 512, 0, stream>>>(xib, xjb, inv_ni, inv_nj, rowsum);
    finalize<<<1, 256, 0, stream>>>(rowsum, diag, (float*)d_out);
}